// Round 6
// baseline (460.513 us; speedup 1.0000x reference)
//
#include <hip/hip_runtime.h>

#define NNODES 100000
#define NEDGES 3200000
#define CH     128
#define KPOOL  50000
#define NBUCK  (1 << 17)          // value buckets for f64 ranking
#define BUCK_SCALE 8192.0         // NBUCK / 16 (range [-8, 8))

// output offsets (floats)
#define OFF_X   0
#define OFF_EI  6400000
#define OFF_EA  12800000
#define OFF_REG 16000000
#define OFF_BAT 16050000
#define OFF_SC  16100000
#define OFF_NE  16200000

#define SCORE_BLK 25000           // score blocks in k_scores_fill
#define FILL_BLK  2344            // prefill blocks (2.4M float4 / 1024)
#define NODE_BLK  512             // k_node grid (barrier participants)
#define EDGE_BLK  782             // ceil(NEDGES / 4096) (barrier participants)
#define POOLB     196             // pool blocks appended to k_edge
#define EPB       4096            // edges per edge block

// ws layout (bytes); zero region = [WS_HIST, WS_TOT)
#define WS_SCORE  0               // 800,000
#define WS_HIST   800000          // 524,288
#define WS_KB     1324288         //  12,544
#define WS_CTR    1336832         //      64  (4 barrier counters)
#define WS_TOT    1336896         //   2,048  (node-scan block totals)
#define WS_EPART  1338944         //  12,512
#define WS_BBASE  1351456         // 524,288
#define WS_ELEMS  1875744         // 400,000
#define WS_PERM   2275744         // 400,000
#define ZERO_U4   33556           // (1336896 - 800000) / 16

__device__ __forceinline__ int bucketOf(double s) {
    double u = (8.0 - s) * BUCK_SCALE;   // monotonic: score desc -> bucket asc
    int b = (int)u;
    if (b < 0) b = 0;
    if (b > NBUCK - 1) b = NBUCK - 1;
    return b;
}

// grid-wide arrive-and-wait barrier (all participating blocks co-resident)
__device__ __forceinline__ void gridbar(unsigned* ctr, unsigned target) {
    __syncthreads();
    if (threadIdx.x == 0) {
        __threadfence();                          // release
        atomicAdd(ctr, 1u);
        while (atomicAdd(ctr, 0u) < target) __builtin_amdgcn_s_sleep(2);
        __threadfence();                          // acquire
    }
    __syncthreads();
    __threadfence();                              // acquire on all threads
}

// Z: zero hist + kb + barrier counters (contiguous)
__global__ void k_init(uint4* __restrict__ z) {
    int idx = blockIdx.x * 256 + threadIdx.x;
    if (idx < ZERO_U4) z[idx] = make_uint4(0u, 0u, 0u, 0u);
}

// K1: scores (f64 accumulate -- bit-identical order) + fused edge-out prefill
__global__ void k_scores_fill(const float* __restrict__ x, const float* __restrict__ W,
                              const float* __restrict__ bias, double* __restrict__ score_d,
                              float* __restrict__ out, unsigned* __restrict__ hist) {
    int bid = blockIdx.x, tid = threadIdx.x;
    if (bid < SCORE_BLK) {
        int row  = bid * 4 + (tid >> 6);
        int lane = tid & 63;
        int c = lane * 2;
        float2 xv = *(const float2*)(x + (size_t)row * CH + c);
        double acc = (double)xv.x * (double)W[c] + (double)xv.y * (double)W[c + 1];
        for (int off = 32; off > 0; off >>= 1) acc += __shfl_down(acc, off, 64);
        if (lane == 0) {
            double s = acc + (double)bias[0];
            score_d[row] = s;
            out[OFF_SC + row] = (float)s;
            atomicAdd(&hist[bucketOf(s)], 1u);
        }
    } else {
        int fb = bid - SCORE_BLK;
        float4* dst = (float4*)(out + OFF_EI);
        const float4 neg = make_float4(-1.f, -1.f, -1.f, -1.f);
        const float4 zer = make_float4(0.f, 0.f, 0.f, 0.f);
#pragma unroll
        for (int q = 0; q < 4; ++q) {
            int f = fb * 1024 + q * 256 + tid;
            if (f < 2400000) dst[f] = (f < 1600000) ? neg : zer;
        }
    }
}

// N: fused hist-scan -> scatter -> rank with 3 grid barriers (512 blocks, all resident)
__global__ __launch_bounds__(256, 4) void k_node(
        const double* __restrict__ score_d, const unsigned* __restrict__ hist,
        unsigned* __restrict__ bbase, unsigned* __restrict__ tot,
        unsigned* __restrict__ elems, unsigned* __restrict__ perm,
        unsigned* __restrict__ kb, unsigned* __restrict__ ctr) {
    int t = threadIdx.x, blk = blockIdx.x;
    __shared__ unsigned sc[256];
    // P1a: local inclusive scan of this block's 256 buckets
    int i0 = blk * 256 + t;
    unsigned h = hist[i0];
    sc[t] = h; __syncthreads();
    for (int off = 1; off < 256; off <<= 1) {
        unsigned v = (t >= off) ? sc[t - off] : 0u;
        __syncthreads(); sc[t] += v; __syncthreads();
    }
    unsigned incl = sc[t];
    if (t == 255) tot[blk] = sc[255];
    gridbar(&ctr[0], NODE_BLK);
    // P1b: sum preceding block totals -> global exclusive bases
    unsigned pr = 0;
    for (int j = t; j < NODE_BLK; j += 256) if (j < blk) pr += tot[j];
    __syncthreads();
    sc[t] = pr; __syncthreads();
    for (int off = 128; off > 0; off >>= 1) {
        if (t < off) sc[t] += sc[t + off];
        __syncthreads();
    }
    unsigned prefix = sc[0];
    __syncthreads();
    bbase[i0] = prefix + incl - h;
    gridbar(&ctr[1], NODE_BLK);
    // P2: scatter node ids (bbase: excl -> excl + count)
    int i = blk * 256 + t;
    if (i < NNODES) {
        int b = bucketOf(score_d[i]);
        unsigned slot = atomicAdd(&bbase[b], 1u);
        elems[slot] = (unsigned)i;
    }
    gridbar(&ctr[2], NODE_BLK);
    // P3: exact rank (desc score, tie -> lower index); st = bbase[b] - hist[b]
    if (i < NNODES) {
        double s = score_d[i];
        int b = bucketOf(s);
        unsigned c = hist[b];
        unsigned st = bbase[b] - c;
        unsigned r = st;
        if (c > 1) {
            for (unsigned m = 0; m < c; ++m) {
                unsigned j = elems[st + m];
                if (j == (unsigned)i) continue;
                double sj = score_d[j];
                if (sj > s || (sj == s && j < (unsigned)i)) r++;
            }
        }
        perm[r] = (unsigned)i;
        if (r < KPOOL) atomicOr(&kb[i >> 5], 1u << (i & 31));
    }
}

// E: single-read edge compaction (1 grid barrier over EDGE_BLK blocks) + pool gather
__global__ __launch_bounds__(256, 4) void k_edge(
        const int* __restrict__ ei, const float* __restrict__ attr,
        const float* __restrict__ x, const int* __restrict__ region,
        const int* __restrict__ batch, const unsigned* __restrict__ perm,
        const unsigned* __restrict__ kb, unsigned* __restrict__ epart,
        unsigned* __restrict__ ctr, float* __restrict__ out) {
    int t = threadIdx.x, bid = blockIdx.x;
    if (bid >= EDGE_BLK) {
        // pool blocks: gather pooled x rows + region/batch (no barrier participation)
        int pb = bid - EDGE_BLK;
        for (int g = pb; g < KPOOL / 4; g += POOLB) {
            int r    = g * 4 + (t >> 6);
            int lane = t & 63;
            unsigned i = perm[r];
            float2 v = *(const float2*)(x + (size_t)i * CH + lane * 2);
            *(float2*)(out + OFF_X + (size_t)r * CH + lane * 2) = v;
            if (lane == 0) {
                out[OFF_REG + r] = (float)region[i];
                out[OFF_BAT + r] = (float)batch[i];
            }
        }
        return;
    }
    __shared__ unsigned sc[256];
    __shared__ float sA[1024], sB[1024], sT[1024];
    size_t base_e = (size_t)bid * EPB;
    int4 aa[4], bb[4]; float4 tt[4];
    unsigned msk[4];
    unsigned cnt = 0;
#pragma unroll
    for (int q = 0; q < 4; ++q) {
        size_t e0 = base_e + (size_t)q * 1024 + (size_t)t * 4;
        unsigned m = 0;
        if (e0 < NEDGES) {
            aa[q] = *(const int4*)(ei + e0);
            bb[q] = *(const int4*)(ei + NEDGES + e0);
            tt[q] = *(const float4*)(attr + e0);
            m  = ((kb[aa[q].x >> 5] >> (aa[q].x & 31)) & (kb[bb[q].x >> 5] >> (bb[q].x & 31)) & 1u);
            m |= ((kb[aa[q].y >> 5] >> (aa[q].y & 31)) & (kb[bb[q].y >> 5] >> (bb[q].y & 31)) & 1u) << 1;
            m |= ((kb[aa[q].z >> 5] >> (aa[q].z & 31)) & (kb[bb[q].z >> 5] >> (bb[q].z & 31)) & 1u) << 2;
            m |= ((kb[aa[q].w >> 5] >> (aa[q].w & 31)) & (kb[bb[q].w >> 5] >> (bb[q].w & 31)) & 1u) << 3;
        } else {
            aa[q] = make_int4(0,0,0,0); bb[q] = make_int4(0,0,0,0);
            tt[q] = make_float4(0,0,0,0);
        }
        msk[q] = m;
        cnt += __popc(m);
    }
    // publish block count
    sc[t] = cnt; __syncthreads();
    for (int off = 128; off > 0; off >>= 1) {
        if (t < off) sc[t] += sc[t + off];
        __syncthreads();
    }
    if (t == 0) epart[bid] = sc[0];
    gridbar(&ctr[3], EDGE_BLK);
    // prefix over preceding blocks + grand total
    unsigned pr = 0, ttl = 0;
    for (int j = t; j < EDGE_BLK; j += 256) {
        unsigned v = epart[j];
        ttl += v;
        if (j < bid) pr += v;
    }
    sc[t] = pr; __syncthreads();
    for (int off = 128; off > 0; off >>= 1) {
        if (t < off) sc[t] += sc[t + off];
        __syncthreads();
    }
    unsigned wbase = sc[0];
    __syncthreads();
    sc[t] = ttl; __syncthreads();
    for (int off = 128; off > 0; off >>= 1) {
        if (t < off) sc[t] += sc[t + off];
        __syncthreads();
    }
    if (bid == 0 && t == 0) out[OFF_NE] = (float)sc[0];
    __syncthreads();
    // stable compaction, 4 subchunks of 1024 edges via LDS staging
#pragma unroll
    for (int q = 0; q < 4; ++q) {
        unsigned m0 = msk[q] & 1u, m1 = (msk[q] >> 1) & 1u,
                 m2 = (msk[q] >> 2) & 1u, m3 = (msk[q] >> 3) & 1u;
        unsigned c = m0 + m1 + m2 + m3;
        sc[t] = c; __syncthreads();
        for (int off = 1; off < 256; off <<= 1) {
            unsigned w = (t >= off) ? sc[t - off] : 0u;
            __syncthreads(); sc[t] += w; __syncthreads();
        }
        unsigned p = sc[t] - c;
        unsigned cAll = sc[255];
        if (m0) { sA[p] = (float)aa[q].x; sB[p] = (float)bb[q].x; sT[p] = tt[q].x; p++; }
        if (m1) { sA[p] = (float)aa[q].y; sB[p] = (float)bb[q].y; sT[p] = tt[q].y; p++; }
        if (m2) { sA[p] = (float)aa[q].z; sB[p] = (float)bb[q].z; sT[p] = tt[q].z; p++; }
        if (m3) { sA[p] = (float)aa[q].w; sB[p] = (float)bb[q].w; sT[p] = tt[q].w; p++; }
        __syncthreads();
        for (unsigned u = t; u < cAll; u += 256) {
            out[OFF_EI + wbase + u]          = sA[u];
            out[OFF_EI + NEDGES + wbase + u] = sB[u];
            out[OFF_EA + wbase + u]          = sT[u];
        }
        wbase += cAll;
        __syncthreads();
    }
    // tail [total, NEDGES) already prefilled with -1/-1/0 by k_scores_fill
}

extern "C" void kernel_launch(void* const* d_in, const int* in_sizes, int n_in,
                              void* d_out, int out_size, void* d_ws, size_t ws_size,
                              hipStream_t stream) {
    const float* x      = (const float*)d_in[0];
    const int*   ei     = (const int*)d_in[1];
    const float* attr   = (const float*)d_in[2];
    const int*   region = (const int*)d_in[3];
    const int*   batch  = (const int*)d_in[4];
    const float* W      = (const float*)d_in[5];
    const float* bias   = (const float*)d_in[6];
    float* out = (float*)d_out;

    char* ws = (char*)d_ws;
    double*   score_d = (double*)(ws + WS_SCORE);
    unsigned* hist    = (unsigned*)(ws + WS_HIST);
    unsigned* kb      = (unsigned*)(ws + WS_KB);
    unsigned* ctr     = (unsigned*)(ws + WS_CTR);
    unsigned* tot     = (unsigned*)(ws + WS_TOT);
    unsigned* epart   = (unsigned*)(ws + WS_EPART);
    unsigned* bbase   = (unsigned*)(ws + WS_BBASE);
    unsigned* elems   = (unsigned*)(ws + WS_ELEMS);
    unsigned* perm    = (unsigned*)(ws + WS_PERM);

    k_init       <<<(ZERO_U4 + 255) / 256, 256, 0, stream>>>((uint4*)(ws + WS_HIST));
    k_scores_fill<<<SCORE_BLK + FILL_BLK, 256, 0, stream>>>(x, W, bias, score_d, out, hist);
    k_node       <<<NODE_BLK, 256, 0, stream>>>(score_d, hist, bbase, tot, elems, perm, kb, ctr);
    k_edge       <<<EDGE_BLK + POOLB, 256, 0, stream>>>(ei, attr, x, region, batch, perm,
                                                        kb, epart, ctr, out);
}

// Round 7
// 133.779 us; speedup vs baseline: 3.4423x; 3.4423x over previous
//
#include <hip/hip_runtime.h>

#define NNODES 100000
#define NEDGES 3200000
#define CH     128
#define KPOOL  50000
#define NBUCK  (1 << 15)          // value buckets for f64 ranking
#define BUCK_SCALE 2048.0         // NBUCK / 16 (range [-8, 8))

// output offsets (floats)
#define OFF_X   0
#define OFF_EI  6400000
#define OFF_EA  12800000
#define OFF_REG 16000000
#define OFF_BAT 16050000
#define OFF_SC  16100000
#define OFF_NE  16200000

#define SCORE_BLK 25000           // score blocks in k_scores_fill
#define FILL_BLK  2344            // prefill blocks (2.4M float4 / 1024)
#define EPB       8192            // edges per k_edge block
#define NBE       391             // ceil(NEDGES / EPB)
#define PUBBIT    (1ULL << 63)

// ws layout (bytes); zero region = [WS_HIST, 946752)
#define WS_SCORE  0               // 800,000
#define WS_HIST   800000          // 131,072
#define WS_KB     931072          //  12,544
#define WS_STATE  943616          //   3,128 (391 x u64 lookback states)
#define WS_TKT    946744          //       8
#define WS_BBASE  946752          // 131,072
#define WS_SPART  1077824         //     128
#define WS_ELEMS  1077952         // 400,000
#define ZERO_U4   9172            // (946752 - 800000) / 16

__device__ __forceinline__ int bucketOf(double s) {
    double u = (8.0 - s) * BUCK_SCALE;   // monotonic: score desc -> bucket asc
    int b = (int)u;
    if (b < 0) b = 0;
    if (b > NBUCK - 1) b = NBUCK - 1;
    return b;
}

// Z: zero hist + kb + states + tickets (contiguous)
__global__ void k_init(uint4* __restrict__ z) {
    int idx = blockIdx.x * 256 + threadIdx.x;
    if (idx < ZERO_U4) z[idx] = make_uint4(0u, 0u, 0u, 0u);
}

// K1: scores (f64 accumulate -- bit-identical order) + fused edge-out prefill
__global__ void k_scores_fill(const float* __restrict__ x, const float* __restrict__ W,
                              const float* __restrict__ bias, double* __restrict__ score_d,
                              float* __restrict__ out, unsigned* __restrict__ hist) {
    int bid = blockIdx.x, tid = threadIdx.x;
    if (bid < SCORE_BLK) {
        int row  = bid * 4 + (tid >> 6);
        int lane = tid & 63;
        int c = lane * 2;
        float2 xv = *(const float2*)(x + (size_t)row * CH + c);
        double acc = (double)xv.x * (double)W[c] + (double)xv.y * (double)W[c + 1];
        for (int off = 32; off > 0; off >>= 1) acc += __shfl_down(acc, off, 64);
        if (lane == 0) {
            double s = acc + (double)bias[0];
            score_d[row] = s;
            out[OFF_SC + row] = (float)s;
            atomicAdd(&hist[bucketOf(s)], 1u);
        }
    } else {
        int fb = bid - SCORE_BLK;
        float4* dst = (float4*)(out + OFF_EI);
        const float4 neg = make_float4(-1.f, -1.f, -1.f, -1.f);
        const float4 zer = make_float4(0.f, 0.f, 0.f, 0.f);
#pragma unroll
        for (int q = 0; q < 4; ++q) {
            int f = fb * 1024 + q * 256 + tid;
            if (f < 2400000) dst[f] = (f < 1600000) ? neg : zer;
        }
    }
}

// S1: 32 blocks scan 1024 buckets each -> local-exclusive bases + block totals
__global__ void k_scan1(const unsigned* __restrict__ hist, unsigned* __restrict__ bbase,
                        unsigned* __restrict__ spart) {
    int t = threadIdx.x, blk = blockIdx.x;
    int i0 = blk * 1024 + t * 4;
    uint4 h = *(const uint4*)(hist + i0);
    unsigned s = h.x + h.y + h.z + h.w;
    __shared__ unsigned sc[256];
    sc[t] = s; __syncthreads();
    for (int off = 1; off < 256; off <<= 1) {
        unsigned v = (t >= off) ? sc[t - off] : 0u;
        __syncthreads(); sc[t] += v; __syncthreads();
    }
    unsigned excl = sc[t] - s;
    if (t == 255) spart[blk] = sc[255];
    uint4 o; o.x = excl; o.y = o.x + h.x; o.z = o.y + h.y; o.w = o.z + h.z;
    *(uint4*)(bbase + i0) = o;
}

// load spart[0..31] and build exclusive prefix in LDS (wave-0 shfl scan)
__device__ __forceinline__ void spart_prefix(const unsigned* __restrict__ spart,
                                             unsigned* sp) {
    int t = threadIdx.x;
    if (t < 64) {
        unsigned v = (t < 32) ? spart[t] : 0u;
        unsigned incl = v;
        for (int off = 1; off < 32; off <<= 1) {
            unsigned w = __shfl_up(incl, off, 64);
            if (t >= off) incl += w;
        }
        if (t < 32) sp[t] = incl - v;
    }
    __syncthreads();
}

// C: scatter node ids into bucket slots (global base = sp[b>>10] + consumed bbase)
__global__ void k_scatter(const double* __restrict__ score_d, const unsigned* __restrict__ spart,
                          unsigned* __restrict__ bbase, unsigned* __restrict__ elems) {
    __shared__ unsigned sp[32];
    spart_prefix(spart, sp);
    int i = blockIdx.x * 256 + threadIdx.x;
    if (i >= NNODES) return;
    int b = bucketOf(score_d[i]);
    unsigned slot = sp[b >> 10] + atomicAdd(&bbase[b], 1u);
    elems[slot] = (unsigned)i;
}

// R+P: exact rank (desc, tie -> lower idx); fused pooled-row copy; keep bits
// post-scatter: bbase[b] = local_excl + hist[b] => st = sp[b>>10] + bbase[b] - hist[b]
__global__ void k_rank_pool(const double* __restrict__ score_d, const unsigned* __restrict__ hist,
                            const unsigned* __restrict__ bbase, const unsigned* __restrict__ spart,
                            const unsigned* __restrict__ elems, const float* __restrict__ x,
                            const int* __restrict__ region, const int* __restrict__ batch,
                            unsigned* __restrict__ kb, float* __restrict__ out) {
    __shared__ unsigned sp[32];
    spart_prefix(spart, sp);
    int i = blockIdx.x * 256 + threadIdx.x;
    if (i >= NNODES) return;
    double s = score_d[i];
    int b = bucketOf(s);
    unsigned c = hist[b];
    unsigned st = sp[b >> 10] + bbase[b] - c;
    unsigned r = st;
    if (c > 1) {
        for (unsigned m = 0; m < c; ++m) {
            unsigned j = elems[st + m];
            if (j == (unsigned)i) continue;
            double sj = score_d[j];
            if (sj > s || (sj == s && j < (unsigned)i)) r++;
        }
    }
    if (r < KPOOL) {
        const float4* src = (const float4*)(x + (size_t)i * CH);
        float4*       dst = (float4*)(out + OFF_X + (size_t)r * CH);
#pragma unroll 8
        for (int q = 0; q < 32; ++q) dst[q] = src[q];
        out[OFF_REG + r] = (float)region[i];
        out[OFF_BAT + r] = (float)batch[i];
        atomicOr(&kb[i >> 5], 1u << (i & 31));
    }
}

// E: single-pass stable edge compaction with wave-parallel decoupled lookback
__global__ __launch_bounds__(256, 2) void k_edge(
        const int* __restrict__ ei, const float* __restrict__ attr,
        const unsigned* __restrict__ kb, unsigned long long* __restrict__ states,
        unsigned* __restrict__ tickets, float* __restrict__ out) {
    int tid = threadIdx.x;
    __shared__ unsigned stkt, sbase_sh;
    __shared__ unsigned sc[256];
    __shared__ float sA[1024], sB[1024], sT[1024];
    if (tid == 0) stkt = atomicAdd(&tickets[0], 1u);
    __syncthreads();
    unsigned blk = stkt;
    size_t base_e = (size_t)blk * EPB;
    // phase 1: count kept edges in this chunk
    unsigned cnt = 0;
    for (int q = 0; q < 8; ++q) {
        size_t e0 = base_e + (size_t)q * 1024 + (size_t)tid * 4;
        if (e0 < NEDGES) {
            int4 a = *(const int4*)(ei + e0);
            int4 b = *(const int4*)(ei + NEDGES + e0);
            cnt += (kb[a.x >> 5] >> (a.x & 31)) & (kb[b.x >> 5] >> (b.x & 31)) & 1u;
            cnt += (kb[a.y >> 5] >> (a.y & 31)) & (kb[b.y >> 5] >> (b.y & 31)) & 1u;
            cnt += (kb[a.z >> 5] >> (a.z & 31)) & (kb[b.z >> 5] >> (b.z & 31)) & 1u;
            cnt += (kb[a.w >> 5] >> (a.w & 31)) & (kb[b.w >> 5] >> (b.w & 31)) & 1u;
        }
    }
    sc[tid] = cnt; __syncthreads();
    for (int off = 128; off > 0; off >>= 1) {
        if (tid < off) sc[tid] += sc[tid + off];
        __syncthreads();
    }
    unsigned total = sc[0];
    __syncthreads();
    // publish own aggregate BEFORE lookback (successors never wait on our lookback)
    if (tid == 0) atomicExch(&states[blk], PUBBIT | (unsigned long long)total);
    // wave-parallel lookback: lane l sums column l, l+64, ... of predecessors
    if (tid < 64) {
        unsigned acc = 0;
        for (int j = tid; j < (int)blk; j += 64) {
            unsigned long long v;
            do {
                v = atomicAdd(&states[j], 0ULL);
                if (!(v >> 63)) __builtin_amdgcn_s_sleep(8);
            } while (!(v >> 63));
            acc += (unsigned)v;
        }
        for (int off = 32; off > 0; off >>= 1) acc += __shfl_down(acc, off, 64);
        if (tid == 0) {
            sbase_sh = acc;
            if (blk == NBE - 1) out[OFF_NE] = (float)(acc + total);
        }
    }
    __syncthreads();
    unsigned wbase = sbase_sh;
    // phase 2: reload (L2-hot), stable LDS-staged compaction, coalesced writes
    for (int q = 0; q < 8; ++q) {
        size_t e0 = base_e + (size_t)q * 1024 + (size_t)tid * 4;
        int4 a = make_int4(0, 0, 0, 0), b = make_int4(0, 0, 0, 0);
        float4 at = make_float4(0.f, 0.f, 0.f, 0.f);
        unsigned m0 = 0, m1 = 0, m2 = 0, m3 = 0;
        if (e0 < NEDGES) {
            a  = *(const int4*)(ei + e0);
            b  = *(const int4*)(ei + NEDGES + e0);
            at = *(const float4*)(attr + e0);
            m0 = (kb[a.x >> 5] >> (a.x & 31)) & (kb[b.x >> 5] >> (b.x & 31)) & 1u;
            m1 = (kb[a.y >> 5] >> (a.y & 31)) & (kb[b.y >> 5] >> (b.y & 31)) & 1u;
            m2 = (kb[a.z >> 5] >> (a.z & 31)) & (kb[b.z >> 5] >> (b.z & 31)) & 1u;
            m3 = (kb[a.w >> 5] >> (a.w & 31)) & (kb[b.w >> 5] >> (b.w & 31)) & 1u;
        }
        unsigned c = m0 + m1 + m2 + m3;
        __syncthreads();
        sc[tid] = c; __syncthreads();
        for (int off = 1; off < 256; off <<= 1) {
            unsigned w = (tid >= off) ? sc[tid - off] : 0u;
            __syncthreads(); sc[tid] += w; __syncthreads();
        }
        unsigned p = sc[tid] - c;
        unsigned cAll = sc[255];
        if (m0) { sA[p] = (float)a.x; sB[p] = (float)b.x; sT[p] = at.x; p++; }
        if (m1) { sA[p] = (float)a.y; sB[p] = (float)b.y; sT[p] = at.y; p++; }
        if (m2) { sA[p] = (float)a.z; sB[p] = (float)b.z; sT[p] = at.z; p++; }
        if (m3) { sA[p] = (float)a.w; sB[p] = (float)b.w; sT[p] = at.w; p++; }
        __syncthreads();
        for (unsigned u = tid; u < cAll; u += 256) {
            out[OFF_EI + wbase + u]          = sA[u];
            out[OFF_EI + NEDGES + wbase + u] = sB[u];
            out[OFF_EA + wbase + u]          = sT[u];
        }
        wbase += cAll;
        __syncthreads();
    }
    // tail [total, NEDGES) already prefilled with -1/-1/0 by k_scores_fill
}

extern "C" void kernel_launch(void* const* d_in, const int* in_sizes, int n_in,
                              void* d_out, int out_size, void* d_ws, size_t ws_size,
                              hipStream_t stream) {
    const float* x      = (const float*)d_in[0];
    const int*   ei     = (const int*)d_in[1];
    const float* attr   = (const float*)d_in[2];
    const int*   region = (const int*)d_in[3];
    const int*   batch  = (const int*)d_in[4];
    const float* W      = (const float*)d_in[5];
    const float* bias   = (const float*)d_in[6];
    float* out = (float*)d_out;

    char* ws = (char*)d_ws;
    double*             score_d = (double*)(ws + WS_SCORE);
    unsigned*           hist    = (unsigned*)(ws + WS_HIST);
    unsigned*           kb      = (unsigned*)(ws + WS_KB);
    unsigned long long* states  = (unsigned long long*)(ws + WS_STATE);
    unsigned*           tickets = (unsigned*)(ws + WS_TKT);
    unsigned*           bbase   = (unsigned*)(ws + WS_BBASE);
    unsigned*           spart   = (unsigned*)(ws + WS_SPART);
    unsigned*           elems   = (unsigned*)(ws + WS_ELEMS);

    k_init       <<<(ZERO_U4 + 255) / 256, 256, 0, stream>>>((uint4*)(ws + WS_HIST));
    k_scores_fill<<<SCORE_BLK + FILL_BLK, 256, 0, stream>>>(x, W, bias, score_d, out, hist);
    k_scan1      <<<32, 256, 0, stream>>>(hist, bbase, spart);
    k_scatter    <<<(NNODES + 255) / 256, 256, 0, stream>>>(score_d, spart, bbase, elems);
    k_rank_pool  <<<(NNODES + 255) / 256, 256, 0, stream>>>(score_d, hist, bbase, spart, elems,
                                                            x, region, batch, kb, out);
    k_edge       <<<NBE, 256, 0, stream>>>(ei, attr, kb, states, tickets, out);
}

// Round 8
// 132.919 us; speedup vs baseline: 3.4646x; 1.0065x over previous
//
#include <hip/hip_runtime.h>

#define NNODES 100000
#define NEDGES 3200000
#define CH     128
#define KPOOL  50000
#define NBUCK  (1 << 15)          // value buckets for f64 ranking
#define BUCK_SCALE 2048.0         // NBUCK / 16 (range [-8, 8))

// output offsets (floats)
#define OFF_X   0
#define OFF_EI  6400000
#define OFF_EA  12800000
#define OFF_REG 16000000
#define OFF_BAT 16050000
#define OFF_SC  16100000
#define OFF_NE  16200000

#define SCORE_BLK 25000           // score blocks in k_scores_fill
#define FILL_BLK  2344            // prefill blocks (2.4M float4 / 1024)
#define EPB       2048            // edges per k_edge block
#define NBE       1563            // ceil(NEDGES / EPB)
#define PUBBIT    (1ULL << 63)

// ws layout (bytes); zero region = [WS_HIST, 956128)
#define WS_SCORE  0               // 800,000
#define WS_HIST   800000          // 131,072
#define WS_KB     931072          //  12,544
#define WS_STATE  943616          //  12,504 (1563 x u64 lookback states)
#define WS_TKT    956120          //       8
#define WS_BBASE  956128          // 131,072
#define WS_SPART  1087200         //     128
#define WS_ELEMS  1087328         // 400,000
#define ZERO_U4   9758            // (956128 - 800000) / 16

__device__ __forceinline__ int bucketOf(double s) {
    double u = (8.0 - s) * BUCK_SCALE;   // monotonic: score desc -> bucket asc
    int b = (int)u;
    if (b < 0) b = 0;
    if (b > NBUCK - 1) b = NBUCK - 1;
    return b;
}

// Z: zero hist + kb + states + tickets (contiguous)
__global__ void k_init(uint4* __restrict__ z) {
    int idx = blockIdx.x * 256 + threadIdx.x;
    if (idx < ZERO_U4) z[idx] = make_uint4(0u, 0u, 0u, 0u);
}

// K1: scores (f64 accumulate -- bit-identical order) + fused edge-out prefill
__global__ void k_scores_fill(const float* __restrict__ x, const float* __restrict__ W,
                              const float* __restrict__ bias, double* __restrict__ score_d,
                              float* __restrict__ out, unsigned* __restrict__ hist) {
    int bid = blockIdx.x, tid = threadIdx.x;
    if (bid < SCORE_BLK) {
        int row  = bid * 4 + (tid >> 6);
        int lane = tid & 63;
        int c = lane * 2;
        float2 xv = *(const float2*)(x + (size_t)row * CH + c);
        double acc = (double)xv.x * (double)W[c] + (double)xv.y * (double)W[c + 1];
        for (int off = 32; off > 0; off >>= 1) acc += __shfl_down(acc, off, 64);
        if (lane == 0) {
            double s = acc + (double)bias[0];
            score_d[row] = s;
            out[OFF_SC + row] = (float)s;
            atomicAdd(&hist[bucketOf(s)], 1u);
        }
    } else {
        int fb = bid - SCORE_BLK;
        float4* dst = (float4*)(out + OFF_EI);
        const float4 neg = make_float4(-1.f, -1.f, -1.f, -1.f);
        const float4 zer = make_float4(0.f, 0.f, 0.f, 0.f);
#pragma unroll
        for (int q = 0; q < 4; ++q) {
            int f = fb * 1024 + q * 256 + tid;
            if (f < 2400000) dst[f] = (f < 1600000) ? neg : zer;
        }
    }
}

// S1: 32 blocks scan 1024 buckets each -> local-exclusive bases + block totals
__global__ void k_scan1(const unsigned* __restrict__ hist, unsigned* __restrict__ bbase,
                        unsigned* __restrict__ spart) {
    int t = threadIdx.x, blk = blockIdx.x;
    int i0 = blk * 1024 + t * 4;
    uint4 h = *(const uint4*)(hist + i0);
    unsigned s = h.x + h.y + h.z + h.w;
    __shared__ unsigned sc[256];
    sc[t] = s; __syncthreads();
    for (int off = 1; off < 256; off <<= 1) {
        unsigned v = (t >= off) ? sc[t - off] : 0u;
        __syncthreads(); sc[t] += v; __syncthreads();
    }
    unsigned excl = sc[t] - s;
    if (t == 255) spart[blk] = sc[255];
    uint4 o; o.x = excl; o.y = o.x + h.x; o.z = o.y + h.y; o.w = o.z + h.z;
    *(uint4*)(bbase + i0) = o;
}

// load spart[0..31] and build exclusive prefix in LDS (wave-0 shfl scan)
__device__ __forceinline__ void spart_prefix(const unsigned* __restrict__ spart,
                                             unsigned* sp) {
    int t = threadIdx.x;
    if (t < 64) {
        unsigned v = (t < 32) ? spart[t] : 0u;
        unsigned incl = v;
        for (int off = 1; off < 32; off <<= 1) {
            unsigned w = __shfl_up(incl, off, 64);
            if (t >= off) incl += w;
        }
        if (t < 32) sp[t] = incl - v;
    }
    __syncthreads();
}

// C: scatter node ids into bucket slots (global base = sp[b>>10] + consumed bbase)
__global__ void k_scatter(const double* __restrict__ score_d, const unsigned* __restrict__ spart,
                          unsigned* __restrict__ bbase, unsigned* __restrict__ elems) {
    __shared__ unsigned sp[32];
    spart_prefix(spart, sp);
    int i = blockIdx.x * 256 + threadIdx.x;
    if (i >= NNODES) return;
    int b = bucketOf(score_d[i]);
    unsigned slot = sp[b >> 10] + atomicAdd(&bbase[b], 1u);
    elems[slot] = (unsigned)i;
}

// R+P: exact rank (desc, tie -> lower idx); keep bits; wave-cooperative pooled-row copy
// post-scatter: bbase[b] = local_excl + hist[b] => st = sp[b>>10] + bbase[b] - hist[b]
__global__ void k_rank_pool(const double* __restrict__ score_d, const unsigned* __restrict__ hist,
                            const unsigned* __restrict__ bbase, const unsigned* __restrict__ spart,
                            const unsigned* __restrict__ elems, const float* __restrict__ x,
                            const int* __restrict__ region, const int* __restrict__ batch,
                            unsigned* __restrict__ kb, float* __restrict__ out) {
    __shared__ unsigned sp[32];
    __shared__ unsigned ski[256], skr[256];
    __shared__ unsigned snk;
    spart_prefix(spart, sp);
    if (threadIdx.x == 0) snk = 0;
    __syncthreads();
    int i = blockIdx.x * 256 + threadIdx.x;
    if (i < NNODES) {
        double s = score_d[i];
        int b = bucketOf(s);
        unsigned c = hist[b];
        unsigned st = sp[b >> 10] + bbase[b] - c;
        unsigned r = st;
        if (c > 1) {
            for (unsigned m = 0; m < c; ++m) {
                unsigned j = elems[st + m];
                if (j == (unsigned)i) continue;
                double sj = score_d[j];
                if (sj > s || (sj == s && j < (unsigned)i)) r++;
            }
        }
        if (r < KPOOL) {
            out[OFF_REG + r] = (float)region[i];
            out[OFF_BAT + r] = (float)batch[i];
            atomicOr(&kb[i >> 5], 1u << (i & 31));
            unsigned slot = atomicAdd(&snk, 1u);
            ski[slot] = (unsigned)i; skr[slot] = r;
        }
    }
    __syncthreads();
    unsigned nk = snk;
    int wid = threadIdx.x >> 6, lane = threadIdx.x & 63;
    for (unsigned idx = wid; idx < nk; idx += 4) {
        unsigned ii = ski[idx], rr = skr[idx];
        float2 v = *(const float2*)(x + (size_t)ii * CH + lane * 2);
        *(float2*)(out + OFF_X + (size_t)rr * CH + lane * 2) = v;
    }
}

// E: single-pass stable edge compaction; shfl scans, regs-only data, wave-parallel lookback
__global__ __launch_bounds__(256, 4) void k_edge(
        const int* __restrict__ ei, const float* __restrict__ attr,
        const unsigned* __restrict__ kb, unsigned long long* __restrict__ states,
        unsigned* __restrict__ tickets, float* __restrict__ out) {
    int tid = threadIdx.x;
    int lane = tid & 63, wid = tid >> 6;
    __shared__ unsigned stkt, sbase_sh;
    __shared__ unsigned wtot[4];
    __shared__ float sA[EPB], sB[EPB], sT[EPB];
    if (tid == 0) stkt = atomicAdd(&tickets[0], 1u);
    __syncthreads();
    unsigned blk = stkt;
    size_t e0 = (size_t)blk * EPB + (size_t)tid * 8;
    int av[8], bv[8]; float tv[8];
    unsigned m = 0;
    if (e0 + 8 <= (size_t)NEDGES) {          // thread ranges are fully in or fully out
        int4 a0 = *(const int4*)(ei + e0);
        int4 a1 = *(const int4*)(ei + e0 + 4);
        int4 b0 = *(const int4*)(ei + NEDGES + e0);
        int4 b1 = *(const int4*)(ei + NEDGES + e0 + 4);
        float4 t0 = *(const float4*)(attr + e0);
        float4 t1 = *(const float4*)(attr + e0 + 4);
        av[0]=a0.x; av[1]=a0.y; av[2]=a0.z; av[3]=a0.w;
        av[4]=a1.x; av[5]=a1.y; av[6]=a1.z; av[7]=a1.w;
        bv[0]=b0.x; bv[1]=b0.y; bv[2]=b0.z; bv[3]=b0.w;
        bv[4]=b1.x; bv[5]=b1.y; bv[6]=b1.z; bv[7]=b1.w;
        tv[0]=t0.x; tv[1]=t0.y; tv[2]=t0.z; tv[3]=t0.w;
        tv[4]=t1.x; tv[5]=t1.y; tv[6]=t1.z; tv[7]=t1.w;
#pragma unroll
        for (int q = 0; q < 8; ++q) {
            unsigned k = (kb[av[q] >> 5] >> (av[q] & 31)) &
                         (kb[bv[q] >> 5] >> (bv[q] & 31)) & 1u;
            m |= k << q;
        }
    }
    unsigned cnt = __popc(m);
    // wave-level inclusive scan (shfl, no LDS)
    unsigned incl = cnt;
    for (int off = 1; off < 64; off <<= 1) {
        unsigned v = __shfl_up(incl, off, 64);
        if (lane >= off) incl += v;
    }
    if (lane == 63) wtot[wid] = incl;
    __syncthreads();
    unsigned wpre = 0, btot = 0;
#pragma unroll
    for (int w = 0; w < 4; ++w) { unsigned v = wtot[w]; if (w < wid) wpre += v; btot += v; }
    unsigned p = wpre + incl - cnt;
    // publish own aggregate BEFORE lookback
    if (tid == 0) atomicExch(&states[blk], PUBBIT | (unsigned long long)btot);
    // wave 0: wave-parallel lookback (waves 1-3 stage concurrently)
    if (wid == 0) {
        unsigned acc = 0;
        for (int j = lane; j < (int)blk; j += 64) {
            unsigned long long v;
            do {
                v = atomicAdd(&states[j], 0ULL);
                if (!(v >> 63)) __builtin_amdgcn_s_sleep(8);
            } while (!(v >> 63));
            acc += (unsigned)v;
        }
        for (int off = 32; off > 0; off >>= 1) acc += __shfl_down(acc, off, 64);
        if (lane == 0) {
            sbase_sh = acc;
            if (blk == NBE - 1) out[OFF_NE] = (float)(acc + btot);
        }
    }
    // stage kept edges (positions disjoint; no pre-sync needed)
#pragma unroll
    for (int q = 0; q < 8; ++q) {
        if ((m >> q) & 1u) {
            sA[p] = (float)av[q]; sB[p] = (float)bv[q]; sT[p] = tv[q]; p++;
        }
    }
    __syncthreads();
    unsigned wbase = sbase_sh;
    for (unsigned u = tid; u < btot; u += 256) {
        out[OFF_EI + wbase + u]          = sA[u];
        out[OFF_EI + NEDGES + wbase + u] = sB[u];
        out[OFF_EA + wbase + u]          = sT[u];
    }
    // tail [total, NEDGES) already prefilled with -1/-1/0 by k_scores_fill
}

extern "C" void kernel_launch(void* const* d_in, const int* in_sizes, int n_in,
                              void* d_out, int out_size, void* d_ws, size_t ws_size,
                              hipStream_t stream) {
    const float* x      = (const float*)d_in[0];
    const int*   ei     = (const int*)d_in[1];
    const float* attr   = (const float*)d_in[2];
    const int*   region = (const int*)d_in[3];
    const int*   batch  = (const int*)d_in[4];
    const float* W      = (const float*)d_in[5];
    const float* bias   = (const float*)d_in[6];
    float* out = (float*)d_out;

    char* ws = (char*)d_ws;
    double*             score_d = (double*)(ws + WS_SCORE);
    unsigned*           hist    = (unsigned*)(ws + WS_HIST);
    unsigned*           kb      = (unsigned*)(ws + WS_KB);
    unsigned long long* states  = (unsigned long long*)(ws + WS_STATE);
    unsigned*           tickets = (unsigned*)(ws + WS_TKT);
    unsigned*           bbase   = (unsigned*)(ws + WS_BBASE);
    unsigned*           spart   = (unsigned*)(ws + WS_SPART);
    unsigned*           elems   = (unsigned*)(ws + WS_ELEMS);

    k_init       <<<(ZERO_U4 + 255) / 256, 256, 0, stream>>>((uint4*)(ws + WS_HIST));
    k_scores_fill<<<SCORE_BLK + FILL_BLK, 256, 0, stream>>>(x, W, bias, score_d, out, hist);
    k_scan1      <<<32, 256, 0, stream>>>(hist, bbase, spart);
    k_scatter    <<<(NNODES + 255) / 256, 256, 0, stream>>>(score_d, spart, bbase, elems);
    k_rank_pool  <<<(NNODES + 255) / 256, 256, 0, stream>>>(score_d, hist, bbase, spart, elems,
                                                            x, region, batch, kb, out);
    k_edge       <<<NBE, 256, 0, stream>>>(ei, attr, kb, states, tickets, out);
}

// Round 9
// 118.563 us; speedup vs baseline: 3.8841x; 1.1211x over previous
//
#include <hip/hip_runtime.h>

#define NNODES 100000
#define NEDGES 3200000
#define CH     128
#define KPOOL  50000
#define NBUCK  (1 << 15)          // value buckets for f64 ranking
#define BUCK_SCALE 2048.0         // NBUCK / 16 (range [-8, 8))

// output offsets (floats)
#define OFF_X   0
#define OFF_EI  6400000
#define OFF_EA  12800000
#define OFF_REG 16000000
#define OFF_BAT 16050000
#define OFF_SC  16100000
#define OFF_NE  16200000

#define SCORE_BLK 25000           // score blocks in k_scores_fill
#define FILL_BLK  2344            // prefill blocks (2.4M float4 / 1024)
#define EPB       2048            // edges per edge chunk
#define NBE       1563            // ceil(NEDGES / EPB)
#define POOLG     12500           // pool blocks (4 rows each)

// ws layout (bytes); zero region = [WS_HIST, WS_BBASE)
#define WS_SCORE  0               // 800,000
#define WS_HIST   800000          // 131,072
#define WS_KB     931072          //  12,544
#define WS_BBASE  943616          // 131,072
#define WS_SPART  1074688         //     128
#define WS_ELEMS  1074816         // 400,000
#define WS_PERM   1474816         // 200,000
#define WS_EPART  1674816         //   6,252
#define ZERO_U4   8976            // (943616 - 800000) / 16

__device__ __forceinline__ int bucketOf(double s) {
    double u = (8.0 - s) * BUCK_SCALE;   // monotonic: score desc -> bucket asc
    int b = (int)u;
    if (b < 0) b = 0;
    if (b > NBUCK - 1) b = NBUCK - 1;
    return b;
}

// Z: zero hist + kb (contiguous)
__global__ void k_init(uint4* __restrict__ z) {
    int idx = blockIdx.x * 256 + threadIdx.x;
    if (idx < ZERO_U4) z[idx] = make_uint4(0u, 0u, 0u, 0u);
}

// K1: scores (f64 accumulate -- bit-identical order) + fused edge-out prefill
__global__ void k_scores_fill(const float* __restrict__ x, const float* __restrict__ W,
                              const float* __restrict__ bias, double* __restrict__ score_d,
                              float* __restrict__ out, unsigned* __restrict__ hist) {
    int bid = blockIdx.x, tid = threadIdx.x;
    if (bid < SCORE_BLK) {
        int row  = bid * 4 + (tid >> 6);
        int lane = tid & 63;
        int c = lane * 2;
        float2 xv = *(const float2*)(x + (size_t)row * CH + c);
        double acc = (double)xv.x * (double)W[c] + (double)xv.y * (double)W[c + 1];
        for (int off = 32; off > 0; off >>= 1) acc += __shfl_down(acc, off, 64);
        if (lane == 0) {
            double s = acc + (double)bias[0];
            score_d[row] = s;
            out[OFF_SC + row] = (float)s;
            atomicAdd(&hist[bucketOf(s)], 1u);
        }
    } else {
        int fb = bid - SCORE_BLK;
        float4* dst = (float4*)(out + OFF_EI);
        const float4 neg = make_float4(-1.f, -1.f, -1.f, -1.f);
        const float4 zer = make_float4(0.f, 0.f, 0.f, 0.f);
#pragma unroll
        for (int q = 0; q < 4; ++q) {
            int f = fb * 1024 + q * 256 + tid;
            if (f < 2400000) dst[f] = (f < 1600000) ? neg : zer;
        }
    }
}

// S1: 32 blocks scan 1024 buckets each -> local-exclusive bases + block totals
__global__ void k_scan1(const unsigned* __restrict__ hist, unsigned* __restrict__ bbase,
                        unsigned* __restrict__ spart) {
    int t = threadIdx.x, blk = blockIdx.x;
    int i0 = blk * 1024 + t * 4;
    uint4 h = *(const uint4*)(hist + i0);
    unsigned s = h.x + h.y + h.z + h.w;
    __shared__ unsigned sc[256];
    sc[t] = s; __syncthreads();
    for (int off = 1; off < 256; off <<= 1) {
        unsigned v = (t >= off) ? sc[t - off] : 0u;
        __syncthreads(); sc[t] += v; __syncthreads();
    }
    unsigned excl = sc[t] - s;
    if (t == 255) spart[blk] = sc[255];
    uint4 o; o.x = excl; o.y = o.x + h.x; o.z = o.y + h.y; o.w = o.z + h.z;
    *(uint4*)(bbase + i0) = o;
}

// load spart[0..31] and build exclusive prefix in LDS (wave-0 shfl scan)
__device__ __forceinline__ void spart_prefix(const unsigned* __restrict__ spart,
                                             unsigned* sp) {
    int t = threadIdx.x;
    if (t < 64) {
        unsigned v = (t < 32) ? spart[t] : 0u;
        unsigned incl = v;
        for (int off = 1; off < 32; off <<= 1) {
            unsigned w = __shfl_up(incl, off, 64);
            if (t >= off) incl += w;
        }
        if (t < 32) sp[t] = incl - v;
    }
    __syncthreads();
}

// C: scatter node ids into bucket slots (global base = sp[b>>10] + consumed bbase)
__global__ void k_scatter(const double* __restrict__ score_d, const unsigned* __restrict__ spart,
                          unsigned* __restrict__ bbase, unsigned* __restrict__ elems) {
    __shared__ unsigned sp[32];
    spart_prefix(spart, sp);
    int i = blockIdx.x * 256 + threadIdx.x;
    if (i >= NNODES) return;
    int b = bucketOf(score_d[i]);
    unsigned slot = sp[b >> 10] + atomicAdd(&bbase[b], 1u);
    elems[slot] = (unsigned)i;
}

// R: exact rank (desc, tie -> lower idx); perm + region/batch + keep bits
// post-scatter: bbase[b] = local_excl + hist[b] => st = sp[b>>10] + bbase[b] - hist[b]
__global__ void k_rank(const double* __restrict__ score_d, const unsigned* __restrict__ hist,
                       const unsigned* __restrict__ bbase, const unsigned* __restrict__ spart,
                       const unsigned* __restrict__ elems, const int* __restrict__ region,
                       const int* __restrict__ batch, unsigned* __restrict__ perm,
                       unsigned* __restrict__ kb, float* __restrict__ out) {
    __shared__ unsigned sp[32];
    spart_prefix(spart, sp);
    int i = blockIdx.x * 256 + threadIdx.x;
    if (i >= NNODES) return;
    double s = score_d[i];
    int b = bucketOf(s);
    unsigned c = hist[b];
    unsigned st = sp[b >> 10] + bbase[b] - c;
    unsigned r = st;
    if (c > 1) {
        for (unsigned m = 0; m < c; ++m) {
            unsigned j = elems[st + m];
            if (j == (unsigned)i) continue;
            double sj = score_d[j];
            if (sj > s || (sj == s && j < (unsigned)i)) r++;
        }
    }
    if (r < KPOOL) {
        perm[r] = (unsigned)i;
        out[OFF_REG + r] = (float)region[i];
        out[OFF_BAT + r] = (float)batch[i];
        atomicOr(&kb[i >> 5], 1u << (i & 31));
    }
}

// P+C: pool gather (wave per row) fused with edge chunk counting
__global__ void k_poolcnt(const float* __restrict__ x, const unsigned* __restrict__ perm,
                          const int* __restrict__ ei, const unsigned* __restrict__ kb,
                          unsigned* __restrict__ epart, float* __restrict__ out) {
    int tid = threadIdx.x, bid = blockIdx.x;
    if (bid < NBE) {
        // count kept edges in chunk bid (2048 edges, 8/thread, ei reads only)
        size_t e0 = (size_t)bid * EPB + (size_t)tid * 8;
        unsigned cnt = 0;
        if (e0 + 8 <= (size_t)NEDGES) {      // 8-edge granules fully in or out
            int4 a0 = *(const int4*)(ei + e0);
            int4 a1 = *(const int4*)(ei + e0 + 4);
            int4 b0 = *(const int4*)(ei + NEDGES + e0);
            int4 b1 = *(const int4*)(ei + NEDGES + e0 + 4);
            cnt += (kb[a0.x >> 5] >> (a0.x & 31)) & (kb[b0.x >> 5] >> (b0.x & 31)) & 1u;
            cnt += (kb[a0.y >> 5] >> (a0.y & 31)) & (kb[b0.y >> 5] >> (b0.y & 31)) & 1u;
            cnt += (kb[a0.z >> 5] >> (a0.z & 31)) & (kb[b0.z >> 5] >> (b0.z & 31)) & 1u;
            cnt += (kb[a0.w >> 5] >> (a0.w & 31)) & (kb[b0.w >> 5] >> (b0.w & 31)) & 1u;
            cnt += (kb[a1.x >> 5] >> (a1.x & 31)) & (kb[b1.x >> 5] >> (b1.x & 31)) & 1u;
            cnt += (kb[a1.y >> 5] >> (a1.y & 31)) & (kb[b1.y >> 5] >> (b1.y & 31)) & 1u;
            cnt += (kb[a1.z >> 5] >> (a1.z & 31)) & (kb[b1.z >> 5] >> (b1.z & 31)) & 1u;
            cnt += (kb[a1.w >> 5] >> (a1.w & 31)) & (kb[b1.w >> 5] >> (b1.w & 31)) & 1u;
        }
        __shared__ unsigned sc[256];
        sc[tid] = cnt; __syncthreads();
        for (int off = 128; off > 0; off >>= 1) {
            if (tid < off) sc[tid] += sc[tid + off];
            __syncthreads();
        }
        if (tid == 0) epart[bid] = sc[0];
    } else {
        // pool: wave per pooled row, fully coalesced 512B granules
        int r    = (bid - NBE) * 4 + (tid >> 6);
        int lane = tid & 63;
        unsigned i = perm[r];
        float2 v = *(const float2*)(x + (size_t)i * CH + lane * 2);
        *(float2*)(out + OFF_X + (size_t)r * CH + lane * 2) = v;
    }
}

// E: stable edge compaction; per-block prefix from epart (L2-hot), no handshakes
__global__ __launch_bounds__(256, 4) void k_escatter(
        const int* __restrict__ ei, const float* __restrict__ attr,
        const unsigned* __restrict__ kb, const unsigned* __restrict__ epart,
        float* __restrict__ out) {
    int tid = threadIdx.x, bid = blockIdx.x;
    int lane = tid & 63, wid = tid >> 6;
    __shared__ unsigned sc[256];
    __shared__ unsigned wtot[4];
    __shared__ float sA[EPB], sB[EPB], sT[EPB];
    size_t e0 = (size_t)bid * EPB + (size_t)tid * 8;
    int av[8], bv[8]; float tv[8];
    unsigned m = 0;
    if (e0 + 8 <= (size_t)NEDGES) {
        int4 a0 = *(const int4*)(ei + e0);
        int4 a1 = *(const int4*)(ei + e0 + 4);
        int4 b0 = *(const int4*)(ei + NEDGES + e0);
        int4 b1 = *(const int4*)(ei + NEDGES + e0 + 4);
        float4 t0 = *(const float4*)(attr + e0);
        float4 t1 = *(const float4*)(attr + e0 + 4);
        av[0]=a0.x; av[1]=a0.y; av[2]=a0.z; av[3]=a0.w;
        av[4]=a1.x; av[5]=a1.y; av[6]=a1.z; av[7]=a1.w;
        bv[0]=b0.x; bv[1]=b0.y; bv[2]=b0.z; bv[3]=b0.w;
        bv[4]=b1.x; bv[5]=b1.y; bv[6]=b1.z; bv[7]=b1.w;
        tv[0]=t0.x; tv[1]=t0.y; tv[2]=t0.z; tv[3]=t0.w;
        tv[4]=t1.x; tv[5]=t1.y; tv[6]=t1.z; tv[7]=t1.w;
#pragma unroll
        for (int q = 0; q < 8; ++q) {
            unsigned k = (kb[av[q] >> 5] >> (av[q] & 31)) &
                         (kb[bv[q] >> 5] >> (bv[q] & 31)) & 1u;
            m |= k << q;
        }
    }
    unsigned cnt = __popc(m);
    // wave-level inclusive scan (shfl)
    unsigned incl = cnt;
    for (int off = 1; off < 64; off <<= 1) {
        unsigned v = __shfl_up(incl, off, 64);
        if (lane >= off) incl += v;
    }
    if (lane == 63) wtot[wid] = incl;
    // per-block global prefix + grand total from epart (6.3 KB, L2-hot)
    unsigned mypr = 0, myttl = 0;
    for (int j = tid; j < NBE; j += 256) {
        unsigned v = epart[j];
        myttl += v;
        if (j < bid) mypr += v;
    }
    __syncthreads();
    unsigned wpre = 0, btot = 0;
#pragma unroll
    for (int w = 0; w < 4; ++w) { unsigned v = wtot[w]; if (w < wid) wpre += v; btot += v; }
    unsigned p = wpre + incl - cnt;
    sc[tid] = mypr; __syncthreads();
    for (int off = 128; off > 0; off >>= 1) {
        if (tid < off) sc[tid] += sc[tid + off];
        __syncthreads();
    }
    unsigned wbase = sc[0];
    __syncthreads();
    if (bid == 0) {
        sc[tid] = myttl; __syncthreads();
        for (int off = 128; off > 0; off >>= 1) {
            if (tid < off) sc[tid] += sc[tid + off];
            __syncthreads();
        }
        if (tid == 0) out[OFF_NE] = (float)sc[0];
    }
    // stage kept edges (disjoint positions)
#pragma unroll
    for (int q = 0; q < 8; ++q) {
        if ((m >> q) & 1u) {
            sA[p] = (float)av[q]; sB[p] = (float)bv[q]; sT[p] = tv[q]; p++;
        }
    }
    __syncthreads();
    for (unsigned u = tid; u < btot; u += 256) {
        out[OFF_EI + wbase + u]          = sA[u];
        out[OFF_EI + NEDGES + wbase + u] = sB[u];
        out[OFF_EA + wbase + u]          = sT[u];
    }
    // tail [total, NEDGES) already prefilled with -1/-1/0 by k_scores_fill
}

extern "C" void kernel_launch(void* const* d_in, const int* in_sizes, int n_in,
                              void* d_out, int out_size, void* d_ws, size_t ws_size,
                              hipStream_t stream) {
    const float* x      = (const float*)d_in[0];
    const int*   ei     = (const int*)d_in[1];
    const float* attr   = (const float*)d_in[2];
    const int*   region = (const int*)d_in[3];
    const int*   batch  = (const int*)d_in[4];
    const float* W      = (const float*)d_in[5];
    const float* bias   = (const float*)d_in[6];
    float* out = (float*)d_out;

    char* ws = (char*)d_ws;
    double*   score_d = (double*)(ws + WS_SCORE);
    unsigned* hist    = (unsigned*)(ws + WS_HIST);
    unsigned* kb      = (unsigned*)(ws + WS_KB);
    unsigned* bbase   = (unsigned*)(ws + WS_BBASE);
    unsigned* spart   = (unsigned*)(ws + WS_SPART);
    unsigned* elems   = (unsigned*)(ws + WS_ELEMS);
    unsigned* perm    = (unsigned*)(ws + WS_PERM);
    unsigned* epart   = (unsigned*)(ws + WS_EPART);

    k_init       <<<(ZERO_U4 + 255) / 256, 256, 0, stream>>>((uint4*)(ws + WS_HIST));
    k_scores_fill<<<SCORE_BLK + FILL_BLK, 256, 0, stream>>>(x, W, bias, score_d, out, hist);
    k_scan1      <<<32, 256, 0, stream>>>(hist, bbase, spart);
    k_scatter    <<<(NNODES + 255) / 256, 256, 0, stream>>>(score_d, spart, bbase, elems);
    k_rank       <<<(NNODES + 255) / 256, 256, 0, stream>>>(score_d, hist, bbase, spart, elems,
                                                            region, batch, perm, kb, out);
    k_poolcnt    <<<NBE + POOLG, 256, 0, stream>>>(x, perm, ei, kb, epart, out);
    k_escatter   <<<NBE, 256, 0, stream>>>(ei, attr, kb, epart, out);
}

// Round 10
// 111.378 us; speedup vs baseline: 4.1347x; 1.0645x over previous
//
#include <hip/hip_runtime.h>

#define NNODES 100000
#define NEDGES 3200000
#define CH     128
#define KPOOL  50000
#define NBUCK  (1 << 15)          // value buckets for f64 ranking
#define BUCK_SCALE 2048.0         // NBUCK / 16 (range [-8, 8))

// output offsets (floats)
#define OFF_X   0
#define OFF_EI  6400000
#define OFF_EA  12800000
#define OFF_REG 16000000
#define OFF_BAT 16050000
#define OFF_SC  16100000
#define OFF_NE  16200000

#define SCORE_BLK 6250            // score blocks (16 rows each) in k_scores_fill
#define FILL_BLK  2344            // prefill blocks (2.4M float4 / 1024)
#define EPB       2048            // edges per edge chunk
#define NBE       1563            // ceil(NEDGES / EPB)
#define POOLG     6250            // pool blocks (8 rows each)

// ws layout (bytes); zero region = [WS_HIST, WS_BBASE)
#define WS_SCORE  0               // 800,000
#define WS_HIST   800000          // 131,072
#define WS_KB     931072          //  12,544
#define WS_BBASE  943616          // 131,072
#define WS_SPART  1074688         //     128
#define WS_ELEMS  1074816         // 400,000
#define WS_PERM   1474816         // 200,000
#define WS_EPART  1674816         //   6,252
#define ZERO_U4   8976            // (943616 - 800000) / 16

__device__ __forceinline__ int bucketOf(double s) {
    double u = (8.0 - s) * BUCK_SCALE;   // monotonic: score desc -> bucket asc
    int b = (int)u;
    if (b < 0) b = 0;
    if (b > NBUCK - 1) b = NBUCK - 1;
    return b;
}

// Z: zero hist + kb (contiguous)
__global__ void k_init(uint4* __restrict__ z) {
    int idx = blockIdx.x * 256 + threadIdx.x;
    if (idx < ZERO_U4) z[idx] = make_uint4(0u, 0u, 0u, 0u);
}

// K1: scores (f64, 16 lanes/row x 8ch, float4 loads) + fused edge-out prefill
__global__ void k_scores_fill(const float* __restrict__ x, const float* __restrict__ W,
                              const float* __restrict__ bias, double* __restrict__ score_d,
                              float* __restrict__ out, unsigned* __restrict__ hist) {
    int bid = blockIdx.x, tid = threadIdx.x;
    if (bid < SCORE_BLK) {
        int row = bid * 16 + (tid >> 4);
        int sl  = tid & 15;
        int c   = sl * 8;
        const float4* xp = (const float4*)(x + (size_t)row * CH + c);
        float4 v0 = xp[0], v1 = xp[1];
        const float* wp = W + c;
        double acc = (double)v0.x * (double)wp[0] + (double)v0.y * (double)wp[1]
                   + (double)v0.z * (double)wp[2] + (double)v0.w * (double)wp[3]
                   + (double)v1.x * (double)wp[4] + (double)v1.y * (double)wp[5]
                   + (double)v1.z * (double)wp[6] + (double)v1.w * (double)wp[7];
        for (int off = 8; off > 0; off >>= 1) acc += __shfl_down(acc, off, 16);
        if (sl == 0) {
            double s = acc + (double)bias[0];
            score_d[row] = s;
            out[OFF_SC + row] = (float)s;
            atomicAdd(&hist[bucketOf(s)], 1u);
        }
    } else {
        int fb = bid - SCORE_BLK;
        float4* dst = (float4*)(out + OFF_EI);
        const float4 neg = make_float4(-1.f, -1.f, -1.f, -1.f);
        const float4 zer = make_float4(0.f, 0.f, 0.f, 0.f);
#pragma unroll
        for (int q = 0; q < 4; ++q) {
            int f = fb * 1024 + q * 256 + tid;
            if (f < 2400000) dst[f] = (f < 1600000) ? neg : zer;
        }
    }
}

// S1: 32 blocks scan 1024 buckets each -> local-exclusive bases + block totals
__global__ void k_scan1(const unsigned* __restrict__ hist, unsigned* __restrict__ bbase,
                        unsigned* __restrict__ spart) {
    int t = threadIdx.x, blk = blockIdx.x;
    int i0 = blk * 1024 + t * 4;
    uint4 h = *(const uint4*)(hist + i0);
    unsigned s = h.x + h.y + h.z + h.w;
    __shared__ unsigned sc[256];
    sc[t] = s; __syncthreads();
    for (int off = 1; off < 256; off <<= 1) {
        unsigned v = (t >= off) ? sc[t - off] : 0u;
        __syncthreads(); sc[t] += v; __syncthreads();
    }
    unsigned excl = sc[t] - s;
    if (t == 255) spart[blk] = sc[255];
    uint4 o; o.x = excl; o.y = o.x + h.x; o.z = o.y + h.y; o.w = o.z + h.z;
    *(uint4*)(bbase + i0) = o;
}

// load spart[0..31] and build exclusive prefix in LDS (wave-0 shfl scan)
__device__ __forceinline__ void spart_prefix(const unsigned* __restrict__ spart,
                                             unsigned* sp) {
    int t = threadIdx.x;
    if (t < 64) {
        unsigned v = (t < 32) ? spart[t] : 0u;
        unsigned incl = v;
        for (int off = 1; off < 32; off <<= 1) {
            unsigned w = __shfl_up(incl, off, 64);
            if (t >= off) incl += w;
        }
        if (t < 32) sp[t] = incl - v;
    }
    __syncthreads();
}

// C: scatter node ids into bucket slots (global base = sp[b>>10] + consumed bbase)
__global__ void k_scatter(const double* __restrict__ score_d, const unsigned* __restrict__ spart,
                          unsigned* __restrict__ bbase, unsigned* __restrict__ elems) {
    __shared__ unsigned sp[32];
    spart_prefix(spart, sp);
    int i = blockIdx.x * 256 + threadIdx.x;
    if (i >= NNODES) return;
    int b = bucketOf(score_d[i]);
    unsigned slot = sp[b >> 10] + atomicAdd(&bbase[b], 1u);
    elems[slot] = (unsigned)i;
}

// R: exact rank (desc, tie -> lower idx); perm + region/batch + keep bits
// post-scatter: bbase[b] = local_excl + hist[b] => st = sp[b>>10] + bbase[b] - hist[b]
__global__ void k_rank(const double* __restrict__ score_d, const unsigned* __restrict__ hist,
                       const unsigned* __restrict__ bbase, const unsigned* __restrict__ spart,
                       const unsigned* __restrict__ elems, const int* __restrict__ region,
                       const int* __restrict__ batch, unsigned* __restrict__ perm,
                       unsigned* __restrict__ kb, float* __restrict__ out) {
    __shared__ unsigned sp[32];
    spart_prefix(spart, sp);
    int i = blockIdx.x * 256 + threadIdx.x;
    if (i >= NNODES) return;
    double s = score_d[i];
    int b = bucketOf(s);
    unsigned c = hist[b];
    unsigned st = sp[b >> 10] + bbase[b] - c;
    unsigned r = st;
    if (c > 1) {
        for (unsigned m = 0; m < c; ++m) {
            unsigned j = elems[st + m];
            if (j == (unsigned)i) continue;
            double sj = score_d[j];
            if (sj > s || (sj == s && j < (unsigned)i)) r++;
        }
    }
    if (r < KPOOL) {
        perm[r] = (unsigned)i;
        out[OFF_REG + r] = (float)region[i];
        out[OFF_BAT + r] = (float)batch[i];
        atomicOr(&kb[i >> 5], 1u << (i & 31));
    }
}

// P+C: pool gather (32 lanes x float4 per row) fused with edge chunk counting
__global__ void k_poolcnt(const float* __restrict__ x, const unsigned* __restrict__ perm,
                          const int* __restrict__ ei, const unsigned* __restrict__ kb,
                          unsigned* __restrict__ epart, float* __restrict__ out) {
    int tid = threadIdx.x, bid = blockIdx.x;
    if (bid < NBE) {
        // count kept edges in chunk bid (2048 edges, 8/thread, ei reads only)
        size_t e0 = (size_t)bid * EPB + (size_t)tid * 8;
        unsigned cnt = 0;
        if (e0 + 8 <= (size_t)NEDGES) {      // 8-edge granules fully in or out
            int4 a0 = *(const int4*)(ei + e0);
            int4 a1 = *(const int4*)(ei + e0 + 4);
            int4 b0 = *(const int4*)(ei + NEDGES + e0);
            int4 b1 = *(const int4*)(ei + NEDGES + e0 + 4);
            cnt += (kb[a0.x >> 5] >> (a0.x & 31)) & (kb[b0.x >> 5] >> (b0.x & 31)) & 1u;
            cnt += (kb[a0.y >> 5] >> (a0.y & 31)) & (kb[b0.y >> 5] >> (b0.y & 31)) & 1u;
            cnt += (kb[a0.z >> 5] >> (a0.z & 31)) & (kb[b0.z >> 5] >> (b0.z & 31)) & 1u;
            cnt += (kb[a0.w >> 5] >> (a0.w & 31)) & (kb[b0.w >> 5] >> (b0.w & 31)) & 1u;
            cnt += (kb[a1.x >> 5] >> (a1.x & 31)) & (kb[b1.x >> 5] >> (b1.x & 31)) & 1u;
            cnt += (kb[a1.y >> 5] >> (a1.y & 31)) & (kb[b1.y >> 5] >> (b1.y & 31)) & 1u;
            cnt += (kb[a1.z >> 5] >> (a1.z & 31)) & (kb[b1.z >> 5] >> (b1.z & 31)) & 1u;
            cnt += (kb[a1.w >> 5] >> (a1.w & 31)) & (kb[b1.w >> 5] >> (b1.w & 31)) & 1u;
        }
        __shared__ unsigned sc[256];
        sc[tid] = cnt; __syncthreads();
        for (int off = 128; off > 0; off >>= 1) {
            if (tid < off) sc[tid] += sc[tid + off];
            __syncthreads();
        }
        if (tid == 0) epart[bid] = sc[0];
    } else {
        // pool: 8 rows/block, 32 lanes x float4 per row (16B/lane, coalesced)
        int r = (bid - NBE) * 8 + (tid >> 5);
        int l = tid & 31;
        unsigned i = perm[r];
        float4 v = *(const float4*)(x + (size_t)i * CH + l * 4);
        *(float4*)(out + OFF_X + (size_t)r * CH + l * 4) = v;
    }
}

// E: stable edge compaction; per-block prefix from epart (L2-hot), no handshakes
__global__ __launch_bounds__(256, 4) void k_escatter(
        const int* __restrict__ ei, const float* __restrict__ attr,
        const unsigned* __restrict__ kb, const unsigned* __restrict__ epart,
        float* __restrict__ out) {
    int tid = threadIdx.x, bid = blockIdx.x;
    int lane = tid & 63, wid = tid >> 6;
    __shared__ unsigned sc[256];
    __shared__ unsigned wtot[4];
    __shared__ float sA[EPB], sB[EPB], sT[EPB];
    size_t e0 = (size_t)bid * EPB + (size_t)tid * 8;
    int av[8], bv[8]; float tv[8];
    unsigned m = 0;
    if (e0 + 8 <= (size_t)NEDGES) {
        int4 a0 = *(const int4*)(ei + e0);
        int4 a1 = *(const int4*)(ei + e0 + 4);
        int4 b0 = *(const int4*)(ei + NEDGES + e0);
        int4 b1 = *(const int4*)(ei + NEDGES + e0 + 4);
        float4 t0 = *(const float4*)(attr + e0);
        float4 t1 = *(const float4*)(attr + e0 + 4);
        av[0]=a0.x; av[1]=a0.y; av[2]=a0.z; av[3]=a0.w;
        av[4]=a1.x; av[5]=a1.y; av[6]=a1.z; av[7]=a1.w;
        bv[0]=b0.x; bv[1]=b0.y; bv[2]=b0.z; bv[3]=b0.w;
        bv[4]=b1.x; bv[5]=b1.y; bv[6]=b1.z; bv[7]=b1.w;
        tv[0]=t0.x; tv[1]=t0.y; tv[2]=t0.z; tv[3]=t0.w;
        tv[4]=t1.x; tv[5]=t1.y; tv[6]=t1.z; tv[7]=t1.w;
#pragma unroll
        for (int q = 0; q < 8; ++q) {
            unsigned k = (kb[av[q] >> 5] >> (av[q] & 31)) &
                         (kb[bv[q] >> 5] >> (bv[q] & 31)) & 1u;
            m |= k << q;
        }
    }
    unsigned cnt = __popc(m);
    // wave-level inclusive scan (shfl)
    unsigned incl = cnt;
    for (int off = 1; off < 64; off <<= 1) {
        unsigned v = __shfl_up(incl, off, 64);
        if (lane >= off) incl += v;
    }
    if (lane == 63) wtot[wid] = incl;
    // per-block global prefix + grand total from epart (6.3 KB, L2-hot)
    unsigned mypr = 0, myttl = 0;
    for (int j = tid; j < NBE; j += 256) {
        unsigned v = epart[j];
        myttl += v;
        if (j < bid) mypr += v;
    }
    __syncthreads();
    unsigned wpre = 0, btot = 0;
#pragma unroll
    for (int w = 0; w < 4; ++w) { unsigned v = wtot[w]; if (w < wid) wpre += v; btot += v; }
    unsigned p = wpre + incl - cnt;
    sc[tid] = mypr; __syncthreads();
    for (int off = 128; off > 0; off >>= 1) {
        if (tid < off) sc[tid] += sc[tid + off];
        __syncthreads();
    }
    unsigned wbase = sc[0];
    __syncthreads();
    if (bid == 0) {
        sc[tid] = myttl; __syncthreads();
        for (int off = 128; off > 0; off >>= 1) {
            if (tid < off) sc[tid] += sc[tid + off];
            __syncthreads();
        }
        if (tid == 0) out[OFF_NE] = (float)sc[0];
    }
    // stage kept edges (disjoint positions)
#pragma unroll
    for (int q = 0; q < 8; ++q) {
        if ((m >> q) & 1u) {
            sA[p] = (float)av[q]; sB[p] = (float)bv[q]; sT[p] = tv[q]; p++;
        }
    }
    __syncthreads();
    for (unsigned u = tid; u < btot; u += 256) {
        out[OFF_EI + wbase + u]          = sA[u];
        out[OFF_EI + NEDGES + wbase + u] = sB[u];
        out[OFF_EA + wbase + u]          = sT[u];
    }
    // tail [total, NEDGES) already prefilled with -1/-1/0 by k_scores_fill
}

extern "C" void kernel_launch(void* const* d_in, const int* in_sizes, int n_in,
                              void* d_out, int out_size, void* d_ws, size_t ws_size,
                              hipStream_t stream) {
    const float* x      = (const float*)d_in[0];
    const int*   ei     = (const int*)d_in[1];
    const float* attr   = (const float*)d_in[2];
    const int*   region = (const int*)d_in[3];
    const int*   batch  = (const int*)d_in[4];
    const float* W      = (const float*)d_in[5];
    const float* bias   = (const float*)d_in[6];
    float* out = (float*)d_out;

    char* ws = (char*)d_ws;
    double*   score_d = (double*)(ws + WS_SCORE);
    unsigned* hist    = (unsigned*)(ws + WS_HIST);
    unsigned* kb      = (unsigned*)(ws + WS_KB);
    unsigned* bbase   = (unsigned*)(ws + WS_BBASE);
    unsigned* spart   = (unsigned*)(ws + WS_SPART);
    unsigned* elems   = (unsigned*)(ws + WS_ELEMS);
    unsigned* perm    = (unsigned*)(ws + WS_PERM);
    unsigned* epart   = (unsigned*)(ws + WS_EPART);

    k_init       <<<(ZERO_U4 + 255) / 256, 256, 0, stream>>>((uint4*)(ws + WS_HIST));
    k_scores_fill<<<SCORE_BLK + FILL_BLK, 256, 0, stream>>>(x, W, bias, score_d, out, hist);
    k_scan1      <<<32, 256, 0, stream>>>(hist, bbase, spart);
    k_scatter    <<<(NNODES + 255) / 256, 256, 0, stream>>>(score_d, spart, bbase, elems);
    k_rank       <<<(NNODES + 255) / 256, 256, 0, stream>>>(score_d, hist, bbase, spart, elems,
                                                            region, batch, perm, kb, out);
    k_poolcnt    <<<NBE + POOLG, 256, 0, stream>>>(x, perm, ei, kb, epart, out);
    k_escatter   <<<NBE, 256, 0, stream>>>(ei, attr, kb, epart, out);
}